// Round 9
// baseline (222.614 us; speedup 1.0000x reference)
//
#include <hip/hip_runtime.h>

typedef unsigned short UST;
typedef unsigned int u32;
typedef __attribute__((ext_vector_type(8))) short short8;
typedef __attribute__((ext_vector_type(4))) float f32x4;

#define HPAD 258
#define CIN 256
#define COUT 512
#define KTOT 2304  // 256*9

// workspace partition (bytes)
#define WB_BYTES (COUT * KTOT * 2)
#define XBT_OFF  WB_BYTES
#define XBT_BYTES (HPAD * HPAD * CIN * 2)
#define ABSM_OFF (XBT_OFF + XBT_BYTES)
#define ABSM_BYTES (HPAD * HPAD * 4)
#define INK_OFF  (ABSM_OFF + ABSM_BYTES)

__device__ __forceinline__ UST f2bf(float f) {
  union { float f; u32 u; } c; c.f = f;
  u32 u = c.u;
  u += 0x7FFFu + ((u >> 16) & 1u);
  return (UST)(u >> 16);
}

__device__ __forceinline__ void gload_lds16(const void* g, void* l) {
  __builtin_amdgcn_global_load_lds(
      (const __attribute__((address_space(1))) u32*)g,
      (__attribute__((address_space(3))) u32*)l, 16, 0, 0);
}

// ---- kernel 1: alpha-fold + reorder weights to [co][khkw*256+ci] bf16 ----
__global__ __launch_bounds__(256) void k_prep_w(const float* __restrict__ w,
                                                UST* __restrict__ wb) {
  int co = blockIdx.x;
  int ci = threadIdx.x;
  const float* wr = w + co * KTOT + ci * 9;
  float v[9];
  float s = 0.f;
#pragma unroll
  for (int j = 0; j < 9; ++j) { v[j] = wr[j]; s += v[j]; }
  __shared__ float red[256];
  red[ci] = s;
  __syncthreads();
#pragma unroll
  for (int off = 128; off > 0; off >>= 1) {
    if (ci < off) red[ci] += red[ci + off];
    __syncthreads();
  }
  float alpha = red[0] * (1.0f / 2304.0f);
  UST* wo = wb + co * KTOT + ci;
#pragma unroll
  for (int j = 0; j < 9; ++j) wo[j * 256] = f2bf(v[j] * alpha);
}

// ---- kernel 2: binarize + NCHW->NHWC transpose + channel-mean |x| ----
__global__ __launch_bounds__(256) void k_binz(const float* __restrict__ x,
                                              UST* __restrict__ xbt,
                                              float* __restrict__ absm) {
  int hp = blockIdx.x;
  int wt = blockIdx.y;
  int wpl = threadIdx.x & 63;
  int chunk = threadIdx.x >> 6;
  int wp = wt * 64 + wpl;
  bool valid = wp < HPAD;
  int hx = hp - 1, wx = wp - 1;
  bool inb = valid && ((unsigned)hx < 256u) && ((unsigned)wx < 256u);
  float asum = 0.f;
  u32 pk[32];
#pragma unroll
  for (int c2 = 0; c2 < 32; ++c2) {
    int ci = chunk * 64 + c2 * 2;
    float v0 = 1.0f, v1 = 1.0f;
    if (inb) {
      v0 = x[(unsigned)ci * 65536u + (unsigned)(hx * 256 + wx)];
      v1 = x[(unsigned)(ci + 1) * 65536u + (unsigned)(hx * 256 + wx)];
    }
    asum += fabsf(v0) + fabsf(v1);
    u32 s0 = (v0 >= 0.f) ? 0x3F80u : 0xBF80u;
    u32 s1 = (v1 >= 0.f) ? 0x3F80u : 0xBF80u;
    pk[c2] = s0 | (s1 << 16);
  }
  if (valid) {
    uint4* dst = (uint4*)(xbt + ((unsigned)(hp * HPAD + wp) * 256u + chunk * 64));
#pragma unroll
    for (int g = 0; g < 8; ++g)
      dst[g] = make_uint4(pk[g * 4], pk[g * 4 + 1], pk[g * 4 + 2], pk[g * 4 + 3]);
  }
  __shared__ float red[4][64];
  red[chunk][wpl] = asum;
  __syncthreads();
  if (chunk == 0 && valid) {
    float tot = red[0][wpl] + red[1][wpl] + red[2][wpl] + red[3][wpl];
    absm[hp * HPAD + wp] = tot * (1.0f / 256.0f);
  }
}

// ---- kernel 3: 3x3 box filter / 9 ----
__global__ __launch_bounds__(256) void k_inputk(const float* __restrict__ absm,
                                                float* __restrict__ inK) {
  int h = blockIdx.x, w = threadIdx.x;
  float s = 0.f;
#pragma unroll
  for (int dh = 0; dh < 3; ++dh)
#pragma unroll
    for (int dw = 0; dw < 3; ++dw) s += absm[(h + dh) * HPAD + (w + dw)];
  inK[h * 256 + w] = s * (1.0f / 9.0f);
}

// ---- kernel 4: 256x256-tile conv, BK=32, 4-slot ring, counted vmcnt ----
// 72 K-steps of 32. LDS = 4 slots x (A 16KB + B 16KB) = 128 KiB.
// Slot plane: 256 rows x 32 k bf16, sr-XOR swizzle (verified conflict-free
// for the 16-row x 4-q read pattern used here):
//   (row,q) -> sr=row>>1, s=((row&1)<<2)|q, byte=sr*128+(s^(sr&7))*16
// Period = 2 tiles (u,u+1), one barrier; stages tiles u+2,u+3; vmcnt NEVER
// drained to 0 in the loop (entry invariant: 4 outstanding = u+1's DMAs):
//   stages(8) | vmcnt(8) | G1 rd | G0 mfma | G2 rd | G1 mfma | G3 rd |
//   G2 mfma | vmcnt(4) | barrier | G0'(u+2) trailing rd | G3 mfma
#define MM(a, b, c) __builtin_amdgcn_mfma_f32_16x16x32_bf16(a, b, c, 0, 0, 0)

#define A_SLOT(S) (lds + (S) * 16384)
#define B_SLOT(S) (lds + 65536 + (S) * 16384)
#define RD_A(S, M) (*(const short8*)(A_SLOT(S) + swzA[M]))
#define RD_B(S, N) (*(const short8*)(B_SLOT(S) + swzB[N]))

#define STAGE_A(SRC, S) do { \
    char* d_ = A_SLOT(S) + wv * 1024; \
    gload_lds16((SRC) + aoff0, d_); \
    gload_lds16((SRC) + aoff1, d_ + 8192); } while (0)

#define STAGE_B(SRC, S) do { \
    char* d_ = B_SLOT(S) + wv * 1024; \
    gload_lds16((SRC) + boff0, d_); \
    gload_lds16((SRC) + boff1, d_ + 8192); } while (0)

#define SB __builtin_amdgcn_sched_barrier(0)

#define MF_LO(AA, BB) \
  __builtin_amdgcn_s_setprio(1); \
  _Pragma("unroll") for (int m = 0; m < 4; ++m) \
  _Pragma("unroll") for (int n = 0; n < 4; ++n) \
    acc[m][n] = MM(AA[m], BB[n], acc[m][n]); \
  __builtin_amdgcn_s_setprio(0);
#define MF_HI(AA, BB) \
  __builtin_amdgcn_s_setprio(1); \
  _Pragma("unroll") for (int m = 0; m < 4; ++m) \
  _Pragma("unroll") for (int n = 0; n < 4; ++n) \
    acc[m + 4][n] = MM(AA[m], BB[n], acc[m + 4][n]); \
  __builtin_amdgcn_s_setprio(0);

// entering: B0_[4] + Alo_[4] hold tile u's B and A(m0-3)
#define PERIOD(S0, S1, T2, T3, A2, A3, BS2, BS3) do { \
  STAGE_A((A2), T2); STAGE_B((BS2), T2); \
  STAGE_A((A3), T3); STAGE_B((BS3), T3); \
  asm volatile("s_waitcnt vmcnt(8)" ::: "memory"); \
  short8 Ahi_[4], B1_[4], A1lo_[4], A1hi_[4]; \
  Ahi_[0] = RD_A(S0, 4); Ahi_[1] = RD_A(S0, 5); \
  Ahi_[2] = RD_A(S0, 6); Ahi_[3] = RD_A(S0, 7); \
  SB; MF_LO(Alo_, B0_); SB; \
  B1_[0] = RD_B(S1, 0); B1_[1] = RD_B(S1, 1); \
  B1_[2] = RD_B(S1, 2); B1_[3] = RD_B(S1, 3); \
  A1lo_[0] = RD_A(S1, 0); A1lo_[1] = RD_A(S1, 1); \
  A1lo_[2] = RD_A(S1, 2); A1lo_[3] = RD_A(S1, 3); \
  SB; MF_HI(Ahi_, B0_); SB; \
  A1hi_[0] = RD_A(S1, 4); A1hi_[1] = RD_A(S1, 5); \
  A1hi_[2] = RD_A(S1, 6); A1hi_[3] = RD_A(S1, 7); \
  SB; MF_LO(A1lo_, B1_); SB; \
  asm volatile("s_waitcnt vmcnt(4)" ::: "memory"); \
  __builtin_amdgcn_s_barrier(); \
  B0_[0] = RD_B(T2, 0); B0_[1] = RD_B(T2, 1); \
  B0_[2] = RD_B(T2, 2); B0_[3] = RD_B(T2, 3); \
  Alo_[0] = RD_A(T2, 0); Alo_[1] = RD_A(T2, 1); \
  Alo_[2] = RD_A(T2, 2); Alo_[3] = RD_A(T2, 3); \
  SB; MF_HI(A1hi_, B1_); SB; \
} while (0)

#define PERIOD_LAST(S0, S1) do { \
  asm volatile("s_waitcnt vmcnt(0)" ::: "memory"); \
  short8 Ahi_[4], B1_[4], A1lo_[4], A1hi_[4]; \
  Ahi_[0] = RD_A(S0, 4); Ahi_[1] = RD_A(S0, 5); \
  Ahi_[2] = RD_A(S0, 6); Ahi_[3] = RD_A(S0, 7); \
  SB; MF_LO(Alo_, B0_); SB; \
  B1_[0] = RD_B(S1, 0); B1_[1] = RD_B(S1, 1); \
  B1_[2] = RD_B(S1, 2); B1_[3] = RD_B(S1, 3); \
  A1lo_[0] = RD_A(S1, 0); A1lo_[1] = RD_A(S1, 1); \
  A1lo_[2] = RD_A(S1, 2); A1lo_[3] = RD_A(S1, 3); \
  SB; MF_HI(Ahi_, B0_); SB; \
  A1hi_[0] = RD_A(S1, 4); A1hi_[1] = RD_A(S1, 5); \
  A1hi_[2] = RD_A(S1, 6); A1hi_[3] = RD_A(S1, 7); \
  SB; MF_LO(A1lo_, B1_); SB; \
  MF_HI(A1hi_, B1_); \
} while (0)

__global__ __launch_bounds__(512, 2) void k_conv8(const UST* __restrict__ wb,
                                                  const UST* __restrict__ xbt,
                                                  const float* __restrict__ inK,
                                                  float* __restrict__ out) {
  __shared__ __align__(16) char lds[131072];
  int tid = threadIdx.x;
  int lane = tid & 63;
  int wv = tid >> 6;
  int wm = wv >> 2, wn = wv & 3;
  int bid = blockIdx.x;
  int bs = (bid & 7) * 64 + (bid >> 3);  // XCD-bijective swizzle (512 % 8 == 0)
  int mt = bs & 1;
  int h = bs >> 1;
  int co0 = mt << 8;

  // staging per-thread offsets (inverse-swizzled global source, linear LDS dest)
  int aoff0, aoff1, boff0, boff1;
  {
    u32 ql0 = (u32)tid * 16u, ql1 = (u32)(512 + tid) * 16u;
    u32 sr0 = ql0 >> 7, s0 = ((ql0 >> 4) & 7u) ^ (sr0 & 7u);
    u32 row0 = (sr0 << 1) | (s0 >> 2), q0 = s0 & 3u;
    u32 sr1 = ql1 >> 7, s1 = ((ql1 >> 4) & 7u) ^ (sr1 & 7u);
    u32 row1 = (sr1 << 1) | (s1 >> 2), q1 = s1 & 3u;
    aoff0 = (co0 + (int)row0) * 4608 + (int)q0 * 16;
    aoff1 = (co0 + (int)row1) * 4608 + (int)q1 * 16;
    boff0 = (int)row0 * 512 + (int)q0 * 16;
    boff1 = (int)row1 * 512 + (int)q1 * 16;
  }
  // ds_read swizzled offsets within a 16KB slot plane
  int swzA[8], swzB[4];
#pragma unroll
  for (int m = 0; m < 8; ++m) {
    u32 row = (u32)(wm * 128 + m * 16 + (lane & 15));
    u32 q = (u32)(lane >> 4);
    u32 sr = row >> 1, s = ((row & 1u) << 2) | q;
    swzA[m] = (int)(sr * 128u + (s ^ (sr & 7u)) * 16u);
  }
#pragma unroll
  for (int n = 0; n < 4; ++n) {
    u32 row = (u32)(wn * 64 + n * 16 + (lane & 15));
    u32 q = (u32)(lane >> 4);
    u32 sr = row >> 1, s = ((row & 1u) << 2) | q;
    swzB[n] = (int)(sr * 128u + (s ^ (sr & 7u)) * 16u);
  }

  const char* wb_b = (const char*)wb;
  const char* xbt_b = (const char*)xbt;

  f32x4 acc[8][4];
#pragma unroll
  for (int m = 0; m < 8; ++m)
#pragma unroll
    for (int n = 0; n < 4; ++n) acc[m][n] = (f32x4){0.f, 0.f, 0.f, 0.f};

  short8 B0_[4], Alo_[4];

  // prologue: stage tiles 0 -> slot0, 1 -> slot1 (8 DMAs); wait tile 0 only
  {
    const char* bg = xbt_b + (h * HPAD) * 512;  // group 0 (kh=0,kw=0)
    STAGE_A(wb_b, 0); STAGE_B(bg, 0);
    STAGE_A(wb_b + 64, 1); STAGE_B(bg + 64, 1);
  }
  asm volatile("s_waitcnt vmcnt(4)" ::: "memory");
  __builtin_amdgcn_s_barrier();
  B0_[0] = RD_B(0, 0); B0_[1] = RD_B(0, 1);
  B0_[2] = RD_B(0, 2); B0_[3] = RD_B(0, 3);
  Alo_[0] = RD_A(0, 0); Alo_[1] = RD_A(0, 1);
  Alo_[2] = RD_A(0, 2); Alo_[3] = RD_A(0, 3);

  // main: 9 khkw groups of 8 tile-32s = 4 periods each
  int kh = 0, kw = 0;
  const char* bcur = xbt_b + (h * HPAD) * 512;
  for (int it = 0; it < 8; ++it) {
    int nkw = kw + 1, nkh = kh;
    if (nkw == 3) { nkw = 0; ++nkh; }
    const char* bnext = xbt_b + ((h + nkh) * HPAD + nkw) * 512;
    const char* ab = wb_b + it * 512;
    PERIOD(0, 1, 2, 3, ab + 128, ab + 192, bcur + 128, bcur + 192);
    PERIOD(2, 3, 0, 1, ab + 256, ab + 320, bcur + 256, bcur + 320);
    PERIOD(0, 1, 2, 3, ab + 384, ab + 448, bcur + 384, bcur + 448);
    PERIOD(2, 3, 0, 1, ab + 512, ab + 576, bnext, bnext + 64);
    kh = nkh; kw = nkw; bcur = bnext;
  }
  {  // group 8 (kh=2, kw=2): tiles 64..71
    const char* ab = wb_b + 8 * 512;
    PERIOD(0, 1, 2, 3, ab + 128, ab + 192, bcur + 128, bcur + 192);
    PERIOD(2, 3, 0, 1, ab + 256, ab + 320, bcur + 256, bcur + 320);
    PERIOD(0, 1, 2, 3, ab + 384, ab + 448, bcur + 384, bcur + 448);
    PERIOD_LAST(2, 3);
  }

  // epilogue: scale by input_K, write NCHW
  int col = lane & 15, rg = lane >> 4;
  int pixbase = h * 256;
#pragma unroll
  for (int n = 0; n < 4; ++n) {
    int w = wn * 64 + n * 16 + col;
    float kv = inK[pixbase + w];
#pragma unroll
    for (int m = 0; m < 8; ++m) {
      int co = co0 + wm * 128 + m * 16 + rg * 4;
      float* o = out + (u32)co * 65536u + (u32)(pixbase + w);
#pragma unroll
      for (int r = 0; r < 4; ++r) o[(u32)r * 65536u] = acc[m][n][r] * kv;
    }
  }
}

extern "C" void kernel_launch(void* const* d_in, const int* in_sizes, int n_in,
                              void* d_out, int out_size, void* d_ws, size_t ws_size,
                              hipStream_t stream) {
  const float* x = (const float*)d_in[0];
  const float* w = (const float*)d_in[1];
  float* out = (float*)d_out;
  char* ws = (char*)d_ws;
  UST* wb = (UST*)ws;
  UST* xbt = (UST*)(ws + XBT_OFF);
  float* absm = (float*)(ws + ABSM_OFF);
  float* inK = (float*)(ws + INK_OFF);

  k_prep_w<<<COUT, 256, 0, stream>>>(w, wb);
  k_binz<<<dim3(HPAD, 5), 256, 0, stream>>>(x, xbt, absm);
  k_inputk<<<256, 256, 0, stream>>>(absm, inK);
  k_conv8<<<512, 512, 0, stream>>>(wb, xbt, inK, out);
}

// Round 10
// 165.562 us; speedup vs baseline: 1.3446x; 1.3446x over previous
//
#include <hip/hip_runtime.h>

typedef unsigned short UST;
typedef unsigned int u32;
typedef __attribute__((ext_vector_type(8))) short short8;
typedef __attribute__((ext_vector_type(4))) float f32x4;

#define HPAD 258
#define CIN 256
#define COUT 512
#define KTOT 2304  // 256*9
#define NT 36      // K-tiles of 64

// workspace partition (bytes)
#define WB_BYTES (COUT * KTOT * 2)
#define XBT_OFF  WB_BYTES
#define XBT_BYTES (HPAD * HPAD * CIN * 2)
#define ABSM_OFF (XBT_OFF + XBT_BYTES)
#define ABSM_BYTES (HPAD * HPAD * 4)
#define INK_OFF  (ABSM_OFF + ABSM_BYTES)

__device__ __forceinline__ UST f2bf(float f) {
  union { float f; u32 u; } c; c.f = f;
  u32 u = c.u;
  u += 0x7FFFu + ((u >> 16) & 1u);
  return (UST)(u >> 16);
}

__device__ __forceinline__ void gload_lds16(const void* g, void* l) {
  __builtin_amdgcn_global_load_lds(
      (const __attribute__((address_space(1))) u32*)g,
      (__attribute__((address_space(3))) u32*)l, 16, 0, 0);
}

// ---- kernel 1: alpha-fold + reorder weights to [co][khkw*256+ci] bf16 ----
__global__ __launch_bounds__(256) void k_prep_w(const float* __restrict__ w,
                                                UST* __restrict__ wb) {
  int co = blockIdx.x;
  int ci = threadIdx.x;
  const float* wr = w + co * KTOT + ci * 9;
  float v[9];
  float s = 0.f;
#pragma unroll
  for (int j = 0; j < 9; ++j) { v[j] = wr[j]; s += v[j]; }
  __shared__ float red[256];
  red[ci] = s;
  __syncthreads();
#pragma unroll
  for (int off = 128; off > 0; off >>= 1) {
    if (ci < off) red[ci] += red[ci + off];
    __syncthreads();
  }
  float alpha = red[0] * (1.0f / 2304.0f);
  UST* wo = wb + co * KTOT + ci;
#pragma unroll
  for (int j = 0; j < 9; ++j) wo[j * 256] = f2bf(v[j] * alpha);
}

// ---- kernel 2: binarize + NCHW->NHWC transpose + channel-mean |x| ----
__global__ __launch_bounds__(256) void k_binz(const float* __restrict__ x,
                                              UST* __restrict__ xbt,
                                              float* __restrict__ absm) {
  int hp = blockIdx.x;
  int wt = blockIdx.y;
  int wpl = threadIdx.x & 63;
  int chunk = threadIdx.x >> 6;
  int wp = wt * 64 + wpl;
  bool valid = wp < HPAD;
  int hx = hp - 1, wx = wp - 1;
  bool inb = valid && ((unsigned)hx < 256u) && ((unsigned)wx < 256u);
  float asum = 0.f;
  u32 pk[32];
#pragma unroll
  for (int c2 = 0; c2 < 32; ++c2) {
    int ci = chunk * 64 + c2 * 2;
    float v0 = 1.0f, v1 = 1.0f;
    if (inb) {
      v0 = x[(unsigned)ci * 65536u + (unsigned)(hx * 256 + wx)];
      v1 = x[(unsigned)(ci + 1) * 65536u + (unsigned)(hx * 256 + wx)];
    }
    asum += fabsf(v0) + fabsf(v1);
    u32 s0 = (v0 >= 0.f) ? 0x3F80u : 0xBF80u;
    u32 s1 = (v1 >= 0.f) ? 0x3F80u : 0xBF80u;
    pk[c2] = s0 | (s1 << 16);
  }
  if (valid) {
    uint4* dst = (uint4*)(xbt + ((unsigned)(hp * HPAD + wp) * 256u + chunk * 64));
#pragma unroll
    for (int g = 0; g < 8; ++g)
      dst[g] = make_uint4(pk[g * 4], pk[g * 4 + 1], pk[g * 4 + 2], pk[g * 4 + 3]);
  }
  __shared__ float red[4][64];
  red[chunk][wpl] = asum;
  __syncthreads();
  if (chunk == 0 && valid) {
    float tot = red[0][wpl] + red[1][wpl] + red[2][wpl] + red[3][wpl];
    absm[hp * HPAD + wp] = tot * (1.0f / 256.0f);
  }
}

// ---- kernel 3: 3x3 box filter / 9 ----
__global__ __launch_bounds__(256) void k_inputk(const float* __restrict__ absm,
                                                float* __restrict__ inK) {
  int h = blockIdx.x, w = threadIdx.x;
  float s = 0.f;
#pragma unroll
  for (int dh = 0; dh < 3; ++dh)
#pragma unroll
    for (int dw = 0; dw < 3; ++dw) s += absm[(h + dh) * HPAD + (w + dw)];
  inK[h * 256 + w] = s * (1.0f / 9.0f);
}

// ---- kernel 4: 256x256-tile conv, ROLE-SPLIT wave schedule ----
// Geometry = R5 best (BK=64, 2 LDS buffers, sr-XOR swizzle, verified 0-conflict).
// Waves wv<4 (Y, lead):  read ks0 | STAGE | MFMA ks0 | read ks1 | MFMA ks1 | bar
// Waves wv>=4 (X, lag):  MFMA ks1(t-1) [carried regs] | read ks0 | STAGE |
//                        MFMA ks0 | read ks1 (carry) | bar
// Each SIMD hosts one Y and one X wave -> while one MFMAs the other owns the
// LDS port; they swap every ~620 cyc. Barrier counts identical both branches.
#define MM(a, b, c) __builtin_amdgcn_mfma_f32_16x16x32_bf16(a, b, c, 0, 0, 0)

#define A_LDS(B, P) (lds + (B) * 32768 + (P) * 16384)
#define B_LDS(B, P) (lds + 65536 + (B) * 32768 + (P) * 16384)
#define RD_A(B, P, M) (*(const short8*)(A_LDS(B, P) + swzA[M]))
#define RD_B(B, P, N) (*(const short8*)(B_LDS(B, P) + swzB[N]))

#define STAGE_A(SRC, P, BUF) do { \
    const char* s_ = (SRC) + (P) * 64; \
    char* d_ = A_LDS(BUF, P) + wv * 1024; \
    gload_lds16(s_ + aoff0, d_); \
    gload_lds16(s_ + aoff1, d_ + 8192); } while (0)

#define STAGE_B(SRC, P, BUF) do { \
    const char* s_ = (SRC) + (P) * 64; \
    char* d_ = B_LDS(BUF, P) + wv * 1024; \
    gload_lds16(s_ + boff0, d_); \
    gload_lds16(s_ + boff1, d_ + 8192); } while (0)

#define STAGE4(ASRC, BSRC, BUF) \
  STAGE_A((ASRC), 0, BUF); STAGE_A((ASRC), 1, BUF); \
  STAGE_B((BSRC), 0, BUF); STAGE_B((BSRC), 1, BUF);

#define SB __builtin_amdgcn_sched_barrier(0)

// read full 12-frag group for k-plane P of buffer BUF
#define RD12(BUF, P, BV, ALO, AHI) \
  BV[0] = RD_B(BUF, P, 0); BV[1] = RD_B(BUF, P, 1); \
  BV[2] = RD_B(BUF, P, 2); BV[3] = RD_B(BUF, P, 3); \
  ALO[0] = RD_A(BUF, P, 0); ALO[1] = RD_A(BUF, P, 1); \
  ALO[2] = RD_A(BUF, P, 2); ALO[3] = RD_A(BUF, P, 3); \
  AHI[0] = RD_A(BUF, P, 4); AHI[1] = RD_A(BUF, P, 5); \
  AHI[2] = RD_A(BUF, P, 6); AHI[3] = RD_A(BUF, P, 7);

#define MFMA32(ALO, AHI, BV) \
  __builtin_amdgcn_s_setprio(1); \
  _Pragma("unroll") for (int m = 0; m < 4; ++m) \
  _Pragma("unroll") for (int n = 0; n < 4; ++n) \
    acc[m][n] = MM(ALO[m], BV[n], acc[m][n]); \
  _Pragma("unroll") for (int m = 0; m < 4; ++m) \
  _Pragma("unroll") for (int n = 0; n < 4; ++n) \
    acc[m + 4][n] = MM(AHI[m], BV[n], acc[m + 4][n]); \
  __builtin_amdgcn_s_setprio(0);

#define VMW(N) asm volatile("s_waitcnt vmcnt(" #N ")" ::: "memory")

// ---- Y (lead) bodies ----
#define BODY_Y(CUR, ASRC, BSRC) do { \
  short8 b0[4], alo0[4], ahi0[4], b1[4], alo1[4], ahi1[4]; \
  RD12(CUR, 0, b0, alo0, ahi0); \
  STAGE4((ASRC), (BSRC), (CUR) ^ 1); \
  SB; MFMA32(alo0, ahi0, b0); SB; \
  RD12(CUR, 1, b1, alo1, ahi1); \
  SB; MFMA32(alo1, ahi1, b1); SB; \
  VMW(0); \
  __builtin_amdgcn_s_barrier(); \
} while (0)

#define BODY_Y_LAST(CUR) do { \
  short8 b0[4], alo0[4], ahi0[4], b1[4], alo1[4], ahi1[4]; \
  RD12(CUR, 0, b0, alo0, ahi0); \
  SB; MFMA32(alo0, ahi0, b0); SB; \
  RD12(CUR, 1, b1, alo1, ahi1); \
  SB; MFMA32(alo1, ahi1, b1); SB; \
} while (0)

// ---- X (lag) bodies; cb/calo/cahi carry ks1 frags of tile t-1 ----
#define BODY_X_FIRST(ASRC, BSRC) do { \
  short8 b0[4], alo0[4], ahi0[4]; \
  RD12(0, 0, b0, alo0, ahi0); \
  STAGE4((ASRC), (BSRC), 1); \
  SB; MFMA32(alo0, ahi0, b0); SB; \
  RD12(0, 1, cb, calo, cahi); \
  VMW(0); \
  __builtin_amdgcn_s_barrier(); \
} while (0)

#define BODY_X(CUR, ASRC, BSRC) do { \
  SB; MFMA32(calo, cahi, cb); SB; \
  short8 b0[4], alo0[4], ahi0[4]; \
  RD12(CUR, 0, b0, alo0, ahi0); \
  STAGE4((ASRC), (BSRC), (CUR) ^ 1); \
  SB; MFMA32(alo0, ahi0, b0); SB; \
  RD12(CUR, 1, cb, calo, cahi); \
  VMW(0); \
  __builtin_amdgcn_s_barrier(); \
} while (0)

#define BODY_X_LAST(CUR) do { \
  SB; MFMA32(calo, cahi, cb); SB; \
  short8 b0[4], alo0[4], ahi0[4]; \
  RD12(CUR, 0, b0, alo0, ahi0); \
  SB; MFMA32(alo0, ahi0, b0); SB; \
  RD12(CUR, 1, cb, calo, cahi); \
  SB; MFMA32(calo, cahi, cb); SB; \
} while (0)

__global__ __launch_bounds__(512, 2) void k_conv8(const UST* __restrict__ wb,
                                                  const UST* __restrict__ xbt,
                                                  const float* __restrict__ inK,
                                                  float* __restrict__ out) {
  __shared__ __align__(16) char lds[131072];
  int tid = threadIdx.x;
  int lane = tid & 63;
  int wv = tid >> 6;
  int wm = wv >> 2, wn = wv & 3;
  int bid = blockIdx.x;
  int bs = (bid & 7) * 64 + (bid >> 3);  // XCD-bijective swizzle (512 % 8 == 0)
  int mt = bs & 1;
  int h = bs >> 1;
  int co0 = mt << 8;

  // staging per-thread offsets (inverse-swizzled global source, linear LDS dest)
  int aoff0, aoff1, boff0, boff1;
  {
    u32 ql0 = (u32)tid * 16u, ql1 = (u32)(512 + tid) * 16u;
    u32 sr0 = ql0 >> 7, s0 = ((ql0 >> 4) & 7u) ^ (sr0 & 7u);
    u32 row0 = (sr0 << 1) | (s0 >> 2), q0 = s0 & 3u;
    u32 sr1 = ql1 >> 7, s1 = ((ql1 >> 4) & 7u) ^ (sr1 & 7u);
    u32 row1 = (sr1 << 1) | (s1 >> 2), q1 = s1 & 3u;
    aoff0 = (co0 + (int)row0) * 4608 + (int)q0 * 16;
    aoff1 = (co0 + (int)row1) * 4608 + (int)q1 * 16;
    boff0 = (int)row0 * 512 + (int)q0 * 16;
    boff1 = (int)row1 * 512 + (int)q1 * 16;
  }
  // ds_read swizzled offsets within a plane
  int swzA[8], swzB[4];
#pragma unroll
  for (int m = 0; m < 8; ++m) {
    u32 row = (u32)(wm * 128 + m * 16 + (lane & 15));
    u32 q = (u32)(lane >> 4);
    u32 sr = row >> 1, s = ((row & 1u) << 2) | q;
    swzA[m] = (int)(sr * 128u + (s ^ (sr & 7u)) * 16u);
  }
#pragma unroll
  for (int n = 0; n < 4; ++n) {
    u32 row = (u32)(wn * 64 + n * 16 + (lane & 15));
    u32 q = (u32)(lane >> 4);
    u32 sr = row >> 1, s = ((row & 1u) << 2) | q;
    swzB[n] = (int)(sr * 128u + (s ^ (sr & 7u)) * 16u);
  }

  const char* wb_b = (const char*)wb;
  const char* xbt_b = (const char*)xbt;

  f32x4 acc[8][4];
#pragma unroll
  for (int m = 0; m < 8; ++m)
#pragma unroll
    for (int n = 0; n < 4; ++n) acc[m][n] = (f32x4){0.f, 0.f, 0.f, 0.f};

  // prologue: stage tile 0 into buf 0 (all waves)
  {
    const char* b0src = xbt_b + (h * HPAD) * 512;  // kh=0, kw=0, c-chunk 0
    STAGE4(wb_b, b0src, 0);
  }
  VMW(0);
  __builtin_amdgcn_s_barrier();

  const char* b0base = xbt_b + (h * HPAD) * 512;

  if (wv < 4) {
    // ---- Y (lead) loop ----
    int kh = 0, kw = 0;
    const char* bcur = b0base;
    for (int it = 0; it < 8; ++it) {
      int nkw = kw + 1, nkh = kh;
      if (nkw == 3) { nkw = 0; ++nkh; }
      const char* bnext = xbt_b + ((h + nkh) * HPAD + nkw) * 512;
      const char* ab = wb_b + it * 512;
      BODY_Y(0, ab + 128, bcur + 128);
      BODY_Y(1, ab + 256, bcur + 256);
      BODY_Y(0, ab + 384, bcur + 384);
      BODY_Y(1, ab + 512, bnext);
      kh = nkh; kw = nkw; bcur = bnext;
    }
    const char* ab = wb_b + 8 * 512;
    BODY_Y(0, ab + 128, bcur + 128);
    BODY_Y(1, ab + 256, bcur + 256);
    BODY_Y(0, ab + 384, bcur + 384);
    BODY_Y_LAST(1);
  } else {
    // ---- X (lag) loop ----
    short8 cb[4], calo[4], cahi[4];
    int kh = 0, kw = 0;
    const char* bcur = b0base;
    {
      const char* ab = wb_b;
      BODY_X_FIRST(ab + 128, bcur + 128);      // region 0, stages t=1
      BODY_X(1, ab + 256, bcur + 256);         // t=1
      BODY_X(0, ab + 384, bcur + 384);         // t=2
      const char* bnext = xbt_b + (h * HPAD + 1) * 512;  // group1: kh=0,kw=1
      BODY_X(1, ab + 512, bnext);              // t=3
      kw = 1; bcur = bnext;
    }
    for (int it = 1; it < 8; ++it) {
      int nkw = kw + 1, nkh = kh;
      if (nkw == 3) { nkw = 0; ++nkh; }
      const char* bnext = xbt_b + ((h + nkh) * HPAD + nkw) * 512;
      const char* ab = wb_b + it * 512;
      BODY_X(0, ab + 128, bcur + 128);
      BODY_X(1, ab + 256, bcur + 256);
      BODY_X(0, ab + 384, bcur + 384);
      BODY_X(1, ab + 512, bnext);
      kh = nkh; kw = nkw; bcur = bnext;
    }
    const char* ab = wb_b + 8 * 512;
    BODY_X(0, ab + 128, bcur + 128);
    BODY_X(1, ab + 256, bcur + 256);
    BODY_X(0, ab + 384, bcur + 384);
    BODY_X_LAST(1);
  }

  // epilogue: scale by input_K, write NCHW
  int col = lane & 15, rg = lane >> 4;
  int pixbase = h * 256;
#pragma unroll
  for (int n = 0; n < 4; ++n) {
    int w = wn * 64 + n * 16 + col;
    float kv = inK[pixbase + w];
#pragma unroll
    for (int m = 0; m < 8; ++m) {
      int co = co0 + wm * 128 + m * 16 + rg * 4;
      float* o = out + (u32)co * 65536u + (u32)(pixbase + w);
#pragma unroll
      for (int r = 0; r < 4; ++r) o[(u32)r * 65536u] = acc[m][n][r] * kv;
    }
  }
}

extern "C" void kernel_launch(void* const* d_in, const int* in_sizes, int n_in,
                              void* d_out, int out_size, void* d_ws, size_t ws_size,
                              hipStream_t stream) {
  const float* x = (const float*)d_in[0];
  const float* w = (const float*)d_in[1];
  float* out = (float*)d_out;
  char* ws = (char*)d_ws;
  UST* wb = (UST*)ws;
  UST* xbt = (UST*)(ws + XBT_OFF);
  float* absm = (float*)(ws + ABSM_OFF);
  float* inK = (float*)(ws + INK_OFF);

  k_prep_w<<<COUT, 256, 0, stream>>>(w, wb);
  k_binz<<<dim3(HPAD, 5), 256, 0, stream>>>(x, xbt, absm);
  k_inputk<<<256, 256, 0, stream>>>(absm, inK);
  k_conv8<<<512, 512, 0, stream>>>(wb, xbt, inK, out);
}

// Round 11
// 160.640 us; speedup vs baseline: 1.3858x; 1.0306x over previous
//
#include <hip/hip_runtime.h>

typedef unsigned short UST;
typedef unsigned int u32;
typedef __attribute__((ext_vector_type(8))) short short8;
typedef __attribute__((ext_vector_type(4))) float f32x4;

#define HPAD 258
#define CIN 256
#define COUT 512
#define KTOT 2304  // 256*9

// workspace partition (bytes)
#define WB_BYTES (COUT * KTOT * 2)
#define XBT_OFF  WB_BYTES
#define XBT_BYTES (HPAD * HPAD * CIN * 2)
#define ABSM_OFF (XBT_OFF + XBT_BYTES)
#define ABSM_BYTES (HPAD * HPAD * 4)
#define INK_OFF  (ABSM_OFF + ABSM_BYTES)

__device__ __forceinline__ UST f2bf(float f) {
  union { float f; u32 u; } c; c.f = f;
  u32 u = c.u;
  u += 0x7FFFu + ((u >> 16) & 1u);
  return (UST)(u >> 16);
}

__device__ __forceinline__ void gload_lds16(const void* g, void* l) {
  __builtin_amdgcn_global_load_lds(
      (const __attribute__((address_space(1))) u32*)g,
      (__attribute__((address_space(3))) u32*)l, 16, 0, 0);
}

// ---- kernel 1: alpha-fold + reorder weights to [co][khkw*256+ci] bf16 ----
__global__ __launch_bounds__(256) void k_prep_w(const float* __restrict__ w,
                                                UST* __restrict__ wb) {
  int co = blockIdx.x;
  int ci = threadIdx.x;
  const float* wr = w + co * KTOT + ci * 9;
  float v[9];
  float s = 0.f;
#pragma unroll
  for (int j = 0; j < 9; ++j) { v[j] = wr[j]; s += v[j]; }
  __shared__ float red[256];
  red[ci] = s;
  __syncthreads();
#pragma unroll
  for (int off = 128; off > 0; off >>= 1) {
    if (ci < off) red[ci] += red[ci + off];
    __syncthreads();
  }
  float alpha = red[0] * (1.0f / 2304.0f);
  UST* wo = wb + co * KTOT + ci;
#pragma unroll
  for (int j = 0; j < 9; ++j) wo[j * 256] = f2bf(v[j] * alpha);
}

// ---- kernel 2: binarize + NCHW->NHWC transpose + channel-mean |x| ----
__global__ __launch_bounds__(256) void k_binz(const float* __restrict__ x,
                                              UST* __restrict__ xbt,
                                              float* __restrict__ absm) {
  int hp = blockIdx.x;
  int wt = blockIdx.y;
  int wpl = threadIdx.x & 63;
  int chunk = threadIdx.x >> 6;
  int wp = wt * 64 + wpl;
  bool valid = wp < HPAD;
  int hx = hp - 1, wx = wp - 1;
  bool inb = valid && ((unsigned)hx < 256u) && ((unsigned)wx < 256u);
  float asum = 0.f;
  u32 pk[32];
#pragma unroll
  for (int c2 = 0; c2 < 32; ++c2) {
    int ci = chunk * 64 + c2 * 2;
    float v0 = 1.0f, v1 = 1.0f;
    if (inb) {
      v0 = x[(unsigned)ci * 65536u + (unsigned)(hx * 256 + wx)];
      v1 = x[(unsigned)(ci + 1) * 65536u + (unsigned)(hx * 256 + wx)];
    }
    asum += fabsf(v0) + fabsf(v1);
    u32 s0 = (v0 >= 0.f) ? 0x3F80u : 0xBF80u;
    u32 s1 = (v1 >= 0.f) ? 0x3F80u : 0xBF80u;
    pk[c2] = s0 | (s1 << 16);
  }
  if (valid) {
    uint4* dst = (uint4*)(xbt + ((unsigned)(hp * HPAD + wp) * 256u + chunk * 64));
#pragma unroll
    for (int g = 0; g < 8; ++g)
      dst[g] = make_uint4(pk[g * 4], pk[g * 4 + 1], pk[g * 4 + 2], pk[g * 4 + 3]);
  }
  __shared__ float red[4][64];
  red[chunk][wpl] = asum;
  __syncthreads();
  if (chunk == 0 && valid) {
    float tot = red[0][wpl] + red[1][wpl] + red[2][wpl] + red[3][wpl];
    absm[hp * HPAD + wp] = tot * (1.0f / 256.0f);
  }
}

// ---- kernel 3: 3x3 box filter / 9 ----
__global__ __launch_bounds__(256) void k_inputk(const float* __restrict__ absm,
                                                float* __restrict__ inK) {
  int h = blockIdx.x, w = threadIdx.x;
  float s = 0.f;
#pragma unroll
  for (int dh = 0; dh < 3; ++dh)
#pragma unroll
    for (int dw = 0; dw < 3; ++dw) s += absm[(h + dh) * HPAD + (w + dw)];
  inK[h * 256 + w] = s * (1.0f / 9.0f);
}

// ---- kernel 4: 256x256-tile conv, counted-vmcnt, A 2-buf + B 3-slot ring ----
// LDS = 160 KiB: A slots lds + S*32768 + P*16384 (S=0,1);
//                B slots lds + 65536 + S*32768 + P*16384 (S=0,1,2).
// Plane: 256 rows x 32 k bf16, sr-XOR swizzle (verified 0-conflict):
//   (row,q) -> sr=row>>1, s=((row&1)<<2)|q, byte=sr*128+(s^(sr&7))*16
// Per tile u: issue A(u+1)x4 then B(u+2)x4; boundary wait = vmcnt(4)
// (A(u+1)+B(u+1) done, both >=1 tile old -> ~0 stall; B(u+2) stays in
// flight ACROSS the barrier -- write-drain off the critical path).
// lgkmcnt(0) before each barrier protects reads vs next tile's restage.
#define MM(a, b, c) __builtin_amdgcn_mfma_f32_16x16x32_bf16(a, b, c, 0, 0, 0)

#define A_LDS(S, P) (lds + (S) * 32768 + (P) * 16384)
#define B_LDS(S, P) (lds + 65536 + (S) * 32768 + (P) * 16384)
#define RD_A(S, P, M) (*(const short8*)(A_LDS(S, P) + swzA[M]))
#define RD_B(S, P, N) (*(const short8*)(B_LDS(S, P) + swzB[N]))

#define STAGE_A(SRC, P, SL) do { \
    const char* s_ = (SRC) + (P) * 64; \
    char* d_ = A_LDS(SL, P) + wv * 1024; \
    gload_lds16(s_ + aoff0, d_); \
    gload_lds16(s_ + aoff1, d_ + 8192); } while (0)

#define STAGE_B(SRC, P, SL) do { \
    const char* s_ = (SRC) + (P) * 64; \
    char* d_ = B_LDS(SL, P) + wv * 1024; \
    gload_lds16(s_ + boff0, d_); \
    gload_lds16(s_ + boff1, d_ + 8192); } while (0)

#define SB __builtin_amdgcn_sched_barrier(0)
#define VMW(N) asm volatile("s_waitcnt vmcnt(" #N ")" ::: "memory")
#define LGK0 asm volatile("s_waitcnt lgkmcnt(0)" ::: "memory")

#define RDB4(S, P, D) \
  D[0] = RD_B(S, P, 0); D[1] = RD_B(S, P, 1); \
  D[2] = RD_B(S, P, 2); D[3] = RD_B(S, P, 3);
#define RDALO(S, P, D) \
  D[0] = RD_A(S, P, 0); D[1] = RD_A(S, P, 1); \
  D[2] = RD_A(S, P, 2); D[3] = RD_A(S, P, 3);
#define RDAHI(S, P, D) \
  D[0] = RD_A(S, P, 4); D[1] = RD_A(S, P, 5); \
  D[2] = RD_A(S, P, 6); D[3] = RD_A(S, P, 7);

#define MF_LO(AA, BB) \
  __builtin_amdgcn_s_setprio(1); \
  _Pragma("unroll") for (int m = 0; m < 4; ++m) \
  _Pragma("unroll") for (int n = 0; n < 4; ++n) \
    acc[m][n] = MM(AA[m], BB[n], acc[m][n]); \
  __builtin_amdgcn_s_setprio(0);
#define MF_HI(AA, BB) \
  __builtin_amdgcn_s_setprio(1); \
  _Pragma("unroll") for (int m = 0; m < 4; ++m) \
  _Pragma("unroll") for (int n = 0; n < 4; ++n) \
    acc[m + 4][n] = MM(AA[m], BB[n], acc[m + 4][n]); \
  __builtin_amdgcn_s_setprio(0);

// B group-base pointer (G = khkw group 0..8, literal)
#define BGP(G) (xbt_b + ((h + (G) / 3) * HPAD + ((G) % 3)) * 512)

// carried across bodies: B0_[4], Alo_[4] = tile-u plane-0 B and A(m0-3)
#define BODY(CA, CB, SA, SBT, TA, TB, ASRC, BSRC) do { \
  short8 Ahi_[4], B1_[4], A1lo_[4], A1hi_[4]; \
  RDAHI(CA, 0, Ahi_); \
  STAGE_A((ASRC), 0, SA); STAGE_A((ASRC), 1, SA); \
  STAGE_B((BSRC), 0, SBT); STAGE_B((BSRC), 1, SBT); \
  SB; MF_LO(Alo_, B0_); SB; \
  RDB4(CB, 1, B1_); RDALO(CA, 1, A1lo_); \
  SB; MF_HI(Ahi_, B0_); SB; \
  RDAHI(CA, 1, A1hi_); \
  SB; MF_LO(A1lo_, B1_); SB; \
  LGK0; VMW(4); \
  __builtin_amdgcn_s_barrier(); \
  RDB4(TB, 0, B0_); RDALO(TA, 0, Alo_); \
  SB; MF_HI(A1hi_, B1_); SB; \
} while (0)

#define BU(U) BODY((U) & 1, (U) % 3, ((U) + 1) & 1, ((U) + 2) % 3, \
                   ((U) + 1) & 1, ((U) + 1) % 3, \
                   wb_b + ((U) + 1) * 128, \
                   BGP(((U) + 2) >> 2) + (((U) + 2) & 3) * 128)

// u = 34: stage A(35) only (B(35) staged at u=33); drain fully
#define BODY34() do { \
  short8 Ahi_[4], B1_[4], A1lo_[4], A1hi_[4]; \
  RDAHI(0, 0, Ahi_); \
  STAGE_A(wb_b + 35 * 128, 0, 1); STAGE_A(wb_b + 35 * 128, 1, 1); \
  SB; MF_LO(Alo_, B0_); SB; \
  RDB4(1, 1, B1_); RDALO(0, 1, A1lo_); \
  SB; MF_HI(Ahi_, B0_); SB; \
  RDAHI(0, 1, A1hi_); \
  SB; MF_LO(A1lo_, B1_); SB; \
  LGK0; VMW(0); \
  __builtin_amdgcn_s_barrier(); \
  RDB4(2, 0, B0_); RDALO(1, 0, Alo_); \
  SB; MF_HI(A1hi_, B1_); SB; \
} while (0)

// u = 35: final tile, no stage/barrier/trailing
#define BODY35() do { \
  short8 Ahi_[4], B1_[4], A1lo_[4], A1hi_[4]; \
  RDAHI(1, 0, Ahi_); \
  SB; MF_LO(Alo_, B0_); SB; \
  RDB4(2, 1, B1_); RDALO(1, 1, A1lo_); \
  SB; MF_HI(Ahi_, B0_); SB; \
  RDAHI(1, 1, A1hi_); \
  SB; MF_LO(A1lo_, B1_); SB; \
  SB; MF_HI(A1hi_, B1_); SB; \
} while (0)

__global__ __launch_bounds__(512, 1) void k_conv8(const UST* __restrict__ wb,
                                                  const UST* __restrict__ xbt,
                                                  const float* __restrict__ inK,
                                                  float* __restrict__ out) {
  __shared__ __align__(16) char lds[163840];
  int tid = threadIdx.x;
  int lane = tid & 63;
  int wv = tid >> 6;
  int wm = wv >> 2, wn = wv & 3;
  int bid = blockIdx.x;
  int bs = (bid & 7) * 64 + (bid >> 3);  // XCD-bijective swizzle (512 % 8 == 0)
  int mt = bs & 1;
  int h = bs >> 1;
  int co0 = mt << 8;

  // staging per-thread offsets (inverse-swizzled global source, linear LDS dest)
  int aoff0, aoff1, boff0, boff1;
  {
    u32 ql0 = (u32)tid * 16u, ql1 = (u32)(512 + tid) * 16u;
    u32 sr0 = ql0 >> 7, s0 = ((ql0 >> 4) & 7u) ^ (sr0 & 7u);
    u32 row0 = (sr0 << 1) | (s0 >> 2), q0 = s0 & 3u;
    u32 sr1 = ql1 >> 7, s1 = ((ql1 >> 4) & 7u) ^ (sr1 & 7u);
    u32 row1 = (sr1 << 1) | (s1 >> 2), q1 = s1 & 3u;
    aoff0 = (co0 + (int)row0) * 4608 + (int)q0 * 16;
    aoff1 = (co0 + (int)row1) * 4608 + (int)q1 * 16;
    boff0 = (int)row0 * 512 + (int)q0 * 16;
    boff1 = (int)row1 * 512 + (int)q1 * 16;
  }
  // ds_read swizzled offsets within a plane
  int swzA[8], swzB[4];
#pragma unroll
  for (int m = 0; m < 8; ++m) {
    u32 row = (u32)(wm * 128 + m * 16 + (lane & 15));
    u32 q = (u32)(lane >> 4);
    u32 sr = row >> 1, s = ((row & 1u) << 2) | q;
    swzA[m] = (int)(sr * 128u + (s ^ (sr & 7u)) * 16u);
  }
#pragma unroll
  for (int n = 0; n < 4; ++n) {
    u32 row = (u32)(wn * 64 + n * 16 + (lane & 15));
    u32 q = (u32)(lane >> 4);
    u32 sr = row >> 1, s = ((row & 1u) << 2) | q;
    swzB[n] = (int)(sr * 128u + (s ^ (sr & 7u)) * 16u);
  }

  const char* wb_b = (const char*)wb;
  const char* xbt_b = (const char*)xbt;

  f32x4 acc[8][4];
#pragma unroll
  for (int m = 0; m < 8; ++m)
#pragma unroll
    for (int n = 0; n < 4; ++n) acc[m][n] = (f32x4){0.f, 0.f, 0.f, 0.f};

  short8 B0_[4], Alo_[4];

  // prologue: A(0)->slot0, B(0)->slot0, B(1)->slot1; wait A0+B0 (B1 in flight)
  STAGE_A(wb_b, 0, 0); STAGE_A(wb_b, 1, 0);
  STAGE_B(BGP(0), 0, 0); STAGE_B(BGP(0), 1, 0);
  STAGE_B(BGP(0) + 128, 0, 1); STAGE_B(BGP(0) + 128, 1, 1);
  VMW(4);
  __builtin_amdgcn_s_barrier();
  RDB4(0, 0, B0_); RDALO(0, 0, Alo_);

  BU(0); BU(1); BU(2); BU(3); BU(4); BU(5); BU(6); BU(7);
  BU(8); BU(9); BU(10); BU(11); BU(12); BU(13); BU(14); BU(15);
  BU(16); BU(17); BU(18); BU(19); BU(20); BU(21); BU(22); BU(23);
  BU(24); BU(25); BU(26); BU(27); BU(28); BU(29); BU(30); BU(31);
  BU(32); BU(33);
  BODY34();
  BODY35();

  // epilogue: scale by input_K, write NCHW
  int col = lane & 15, rg = lane >> 4;
  int pixbase = h * 256;
#pragma unroll
  for (int n = 0; n < 4; ++n) {
    int w = wn * 64 + n * 16 + col;
    float kv = inK[pixbase + w];
#pragma unroll
    for (int m = 0; m < 8; ++m) {
      int co = co0 + wm * 128 + m * 16 + rg * 4;
      float* o = out + (u32)co * 65536u + (u32)(pixbase + w);
#pragma unroll
      for (int r = 0; r < 4; ++r) o[(u32)r * 65536u] = acc[m][n][r] * kv;
    }
  }
}

extern "C" void kernel_launch(void* const* d_in, const int* in_sizes, int n_in,
                              void* d_out, int out_size, void* d_ws, size_t ws_size,
                              hipStream_t stream) {
  const float* x = (const float*)d_in[0];
  const float* w = (const float*)d_in[1];
  float* out = (float*)d_out;
  char* ws = (char*)d_ws;
  UST* wb = (UST*)ws;
  UST* xbt = (UST*)(ws + XBT_OFF);
  float* absm = (float*)(ws + ABSM_OFF);
  float* inK = (float*)(ws + INK_OFF);

  k_prep_w<<<COUT, 256, 0, stream>>>(w, wb);
  k_binz<<<dim3(HPAD, 5), 256, 0, stream>>>(x, xbt, absm);
  k_inputk<<<256, 256, 0, stream>>>(absm, inK);
  k_conv8<<<512, 512, 0, stream>>>(wb, xbt, inK, out);
}

// Round 12
// 110.344 us; speedup vs baseline: 2.0174x; 1.4558x over previous
//
#include <hip/hip_runtime.h>

typedef unsigned short UST;
typedef unsigned int u32;
typedef __attribute__((ext_vector_type(4))) int i32x4;

#define HPAD 258
#define CIN 256
#define COUT 512
#define KTOT 2304  // 256*9

// workspace partition (bytes)
#define SCALES_OFF (COUT * KTOT)           // 1,179,648 (i8 weights first)
#define XBT_OFF    (SCALES_OFF + 2048)     // 1,181,696 (16B aligned)
#define XBT_BYTES  (HPAD * HPAD * CIN)     // 17,040,384 (i8)
#define ABSM_OFF   (XBT_OFF + XBT_BYTES)
#define ABSM_BYTES (HPAD * HPAD * 4)
#define INK_OFF    (ABSM_OFF + ABSM_BYTES)

__device__ __forceinline__ void gload_lds16(const void* g, void* l) {
  __builtin_amdgcn_global_load_lds(
      (const __attribute__((address_space(1))) u32*)g,
      (__attribute__((address_space(3))) u32*)l, 16, 0, 0);
}

// ---- kernel 1: per-channel i8 quant + alpha-fold scale ----
// wq[co][khkw*256+ci] = round(127*w/max|w|_co); scales[co] = alpha*max|w|/127
__global__ __launch_bounds__(256) void k_prep_w(const float* __restrict__ w,
                                                signed char* __restrict__ wq,
                                                float* __restrict__ scales) {
  int co = blockIdx.x;
  int ci = threadIdx.x;
  const float* wr = w + co * KTOT + ci * 9;
  float v[9];
  float s = 0.f, mx = 0.f;
#pragma unroll
  for (int j = 0; j < 9; ++j) {
    v[j] = wr[j]; s += v[j]; mx = fmaxf(mx, fabsf(v[j]));
  }
  __shared__ float redS[256];
  __shared__ float redM[256];
  redS[ci] = s; redM[ci] = mx;
  __syncthreads();
#pragma unroll
  for (int off = 128; off > 0; off >>= 1) {
    if (ci < off) {
      redS[ci] += redS[ci + off];
      redM[ci] = fmaxf(redM[ci], redM[ci + off]);
    }
    __syncthreads();
  }
  float alpha = redS[0] * (1.0f / 2304.0f);
  float maxw = redM[0];
  float inv = 127.0f / maxw;
  signed char* wo = wq + co * KTOT + ci;
#pragma unroll
  for (int j = 0; j < 9; ++j)
    wo[j * 256] = (signed char)__float2int_rn(v[j] * inv);
  if (ci == 0) scales[co] = alpha * maxw * (1.0f / 127.0f);
}

// ---- kernel 2: binarize to i8 (+1/-1) NHWC + channel-mean |x| ----
__global__ __launch_bounds__(256) void k_binz(const float* __restrict__ x,
                                              signed char* __restrict__ xbt,
                                              float* __restrict__ absm) {
  int hp = blockIdx.x;
  int wt = blockIdx.y;
  int wpl = threadIdx.x & 63;
  int chunk = threadIdx.x >> 6;
  int wp = wt * 64 + wpl;
  bool valid = wp < HPAD;
  int hx = hp - 1, wx = wp - 1;
  bool inb = valid && ((unsigned)hx < 256u) && ((unsigned)wx < 256u);
  float asum = 0.f;
  u32 pk[16];
#pragma unroll
  for (int c4 = 0; c4 < 16; ++c4) {
    u32 word = 0;
#pragma unroll
    for (int b = 0; b < 4; ++b) {
      int ci = chunk * 64 + c4 * 4 + b;
      float v = 1.0f;
      if (inb) v = x[(unsigned)ci * 65536u + (unsigned)(hx * 256 + wx)];
      asum += fabsf(v);
      u32 byte = (v >= 0.f) ? 0x01u : 0xFFu;
      word |= byte << (8 * b);
    }
    pk[c4] = word;
  }
  if (valid) {
    uint4* dst = (uint4*)(xbt + (unsigned)(hp * HPAD + wp) * 256u + chunk * 64);
#pragma unroll
    for (int g = 0; g < 4; ++g)
      dst[g] = make_uint4(pk[g * 4], pk[g * 4 + 1], pk[g * 4 + 2], pk[g * 4 + 3]);
  }
  __shared__ float red[4][64];
  red[chunk][wpl] = asum;
  __syncthreads();
  if (chunk == 0 && valid) {
    float tot = red[0][wpl] + red[1][wpl] + red[2][wpl] + red[3][wpl];
    absm[hp * HPAD + wp] = tot * (1.0f / 256.0f);
  }
}

// ---- kernel 3: 3x3 box filter / 9 ----
__global__ __launch_bounds__(256) void k_inputk(const float* __restrict__ absm,
                                                float* __restrict__ inK) {
  int h = blockIdx.x, w = threadIdx.x;
  float s = 0.f;
#pragma unroll
  for (int dh = 0; dh < 3; ++dh)
#pragma unroll
    for (int dw = 0; dw < 3; ++dw) s += absm[(h + dh) * HPAD + (w + dw)];
  inK[h * 256 + w] = s * (1.0f / 9.0f);
}

// ---- kernel 4: 256x256-tile conv, i8 MFMA (16x16x64), BK=128, 18 K-tiles ----
// LDS (128 KiB): A buf: lds + BUF*32768 (256 rows x 128 k i8 = 32 KB);
//                B buf: lds + 65536 + BUF*32768.
// Row = 128 B = 8 slots of 16 B, XOR swizzle byte = row*128 + (slot^(row&7))*16
// (same verified-conflict-free family as R5: lanes 0-15 span all 32 banks 2-way).
// Frags: A lane l: row = l&15 (+16*m +128*wm), 16 i8 at k-slot (l>>4)+4*ks.
// C/D layout dtype-independent (verified): col=lane&15, row=(lane>>4)*4+reg.
// Per tile: read ks0 (12 frags) | stage next tile (8 DMAs) | MFMA ks0 (32) |
//           read ks1 | MFMA ks1 | vmcnt(0) barrier.   18+18 execs/CU.
#define MMI(a, b, c) __builtin_amdgcn_mfma_i32_16x16x64_i8(a, b, c, 0, 0, 0)

#define A_LDS(BUF) (lds + (BUF) * 32768)
#define B_LDS(BUF) (lds + 65536 + (BUF) * 32768)
#define RD_A(BUF, KS, M) (*(const i32x4*)(A_LDS(BUF) + swzA[KS][M]))
#define RD_B(BUF, KS, N) (*(const i32x4*)(B_LDS(BUF) + swzB[KS][N]))

#define STAGE_A(SRC, BUF) do { \
    char* d_ = A_LDS(BUF) + wv * 1024; \
    gload_lds16((SRC) + aoff[0], d_); \
    gload_lds16((SRC) + aoff[1], d_ + 8192); \
    gload_lds16((SRC) + aoff[2], d_ + 16384); \
    gload_lds16((SRC) + aoff[3], d_ + 24576); } while (0)

#define STAGE_B(SRC, BUF) do { \
    char* d_ = B_LDS(BUF) + wv * 1024; \
    gload_lds16((SRC) + boff[0], d_); \
    gload_lds16((SRC) + boff[1], d_ + 8192); \
    gload_lds16((SRC) + boff[2], d_ + 16384); \
    gload_lds16((SRC) + boff[3], d_ + 24576); } while (0)

#define SB __builtin_amdgcn_sched_barrier(0)

#define RD12(BUF, KS, BV, ALO, AHI) \
  BV[0] = RD_B(BUF, KS, 0); BV[1] = RD_B(BUF, KS, 1); \
  BV[2] = RD_B(BUF, KS, 2); BV[3] = RD_B(BUF, KS, 3); \
  ALO[0] = RD_A(BUF, KS, 0); ALO[1] = RD_A(BUF, KS, 1); \
  ALO[2] = RD_A(BUF, KS, 2); ALO[3] = RD_A(BUF, KS, 3); \
  AHI[0] = RD_A(BUF, KS, 4); AHI[1] = RD_A(BUF, KS, 5); \
  AHI[2] = RD_A(BUF, KS, 6); AHI[3] = RD_A(BUF, KS, 7);

#define MFMA32(ALO, AHI, BV) \
  __builtin_amdgcn_s_setprio(1); \
  _Pragma("unroll") for (int m = 0; m < 4; ++m) \
  _Pragma("unroll") for (int n = 0; n < 4; ++n) \
    acc[m][n] = MMI(ALO[m], BV[n], acc[m][n]); \
  _Pragma("unroll") for (int m = 0; m < 4; ++m) \
  _Pragma("unroll") for (int n = 0; n < 4; ++n) \
    acc[m + 4][n] = MMI(AHI[m], BV[n], acc[m + 4][n]); \
  __builtin_amdgcn_s_setprio(0);

#define BODY(CUR, ASRC, BSRC) do { \
  i32x4 b0[4], alo0[4], ahi0[4], b1[4], alo1[4], ahi1[4]; \
  RD12(CUR, 0, b0, alo0, ahi0); \
  STAGE_A((ASRC), (CUR) ^ 1); STAGE_B((BSRC), (CUR) ^ 1); \
  SB; MFMA32(alo0, ahi0, b0); SB; \
  RD12(CUR, 1, b1, alo1, ahi1); \
  SB; MFMA32(alo1, ahi1, b1); SB; \
  asm volatile("s_waitcnt vmcnt(0)" ::: "memory"); \
  __builtin_amdgcn_s_barrier(); \
} while (0)

#define BODY_LAST(CUR) do { \
  i32x4 b0[4], alo0[4], ahi0[4], b1[4], alo1[4], ahi1[4]; \
  RD12(CUR, 0, b0, alo0, ahi0); \
  SB; MFMA32(alo0, ahi0, b0); SB; \
  RD12(CUR, 1, b1, alo1, ahi1); \
  SB; MFMA32(alo1, ahi1, b1); SB; \
} while (0)

__global__ __launch_bounds__(512, 2) void k_conv8(const signed char* __restrict__ wq,
                                                  const signed char* __restrict__ xbt,
                                                  const float* __restrict__ scales,
                                                  const float* __restrict__ inK,
                                                  float* __restrict__ out) {
  __shared__ __align__(16) char lds[131072];
  int tid = threadIdx.x;
  int lane = tid & 63;
  int wv = tid >> 6;
  int wm = wv >> 2, wn = wv & 3;
  int bid = blockIdx.x;
  int bs = (bid & 7) * 64 + (bid >> 3);  // XCD-bijective swizzle (512 % 8 == 0)
  int mt = bs & 1;
  int h = bs >> 1;
  int co0 = mt << 8;

  // staging offsets: inverse-swizzled global source, linear LDS dest
  int aoff[4], boff[4];
#pragma unroll
  for (int i = 0; i < 4; ++i) {
    u32 ql = (u32)(i * 512 + tid) * 16u;
    u32 row = ql >> 7;
    u32 s = (ql >> 4) & 7u;
    u32 slot = s ^ (row & 7u);
    aoff[i] = (int)((co0 + row) * 2304u + slot * 16u);
    boff[i] = (int)(row * 256u + slot * 16u);
  }
  // ds_read swizzled offsets: [ks][frag]
  int swzA[2][8], swzB[2][4];
#pragma unroll
  for (int ks = 0; ks < 2; ++ks) {
#pragma unroll
    for (int m = 0; m < 8; ++m) {
      u32 row = (u32)(wm * 128 + m * 16 + (lane & 15));
      u32 slot = (u32)(ks * 4 + (lane >> 4));
      swzA[ks][m] = (int)(row * 128u + (slot ^ (row & 7u)) * 16u);
    }
#pragma unroll
    for (int n = 0; n < 4; ++n) {
      u32 row = (u32)(wn * 64 + n * 16 + (lane & 15));
      u32 slot = (u32)(ks * 4 + (lane >> 4));
      swzB[ks][n] = (int)(row * 128u + (slot ^ (row & 7u)) * 16u);
    }
  }

  const char* wb_b = (const char*)wq;
  const char* xbt_b = (const char*)xbt;

  i32x4 acc[8][4];
#pragma unroll
  for (int m = 0; m < 8; ++m)
#pragma unroll
    for (int n = 0; n < 4; ++n) acc[m][n] = (i32x4){0, 0, 0, 0};

  // prologue: stage tile 0 into buf 0
  STAGE_A(wb_b, 0);
  STAGE_B(xbt_b + (h * HPAD) * 256, 0);
  asm volatile("s_waitcnt vmcnt(0)" ::: "memory");
  __builtin_amdgcn_s_barrier();

  // 18 K-tiles of 128 (9 khkw groups x 2 ci-halves), fully unrolled
#pragma unroll
  for (int t = 0; t < 17; ++t) {
    int tn = t + 1;
    int g = tn >> 1;
    int gh = g / 3, gw = g % 3;
    const char* asrc = wb_b + tn * 128;
    const char* bsrc = xbt_b + ((h + gh) * HPAD + gw) * 256 + (tn & 1) * 128;
    if (t & 1) { BODY(1, asrc, bsrc); }
    else       { BODY(0, asrc, bsrc); }
  }
  BODY_LAST(1);  // t = 17

  // epilogue: out = acc * scale[co] * input_K, write NCHW
  int col = lane & 15, rg = lane >> 4;
  int pixbase = h * 256;
#pragma unroll
  for (int n = 0; n < 4; ++n) {
    int w = wn * 64 + n * 16 + col;
    float kv = inK[pixbase + w];
#pragma unroll
    for (int m = 0; m < 8; ++m) {
      int cobase = co0 + wm * 128 + m * 16 + rg * 4;
      float4 scv = *(const float4*)(scales + cobase);
      float* o = out + (u32)cobase * 65536u + (u32)(pixbase + w);
      o[0]          = (float)acc[m][n][0] * scv.x * kv;
      o[65536u]     = (float)acc[m][n][1] * scv.y * kv;
      o[2u * 65536u] = (float)acc[m][n][2] * scv.z * kv;
      o[3u * 65536u] = (float)acc[m][n][3] * scv.w * kv;
    }
  }
}

extern "C" void kernel_launch(void* const* d_in, const int* in_sizes, int n_in,
                              void* d_out, int out_size, void* d_ws, size_t ws_size,
                              hipStream_t stream) {
  const float* x = (const float*)d_in[0];
  const float* w = (const float*)d_in[1];
  float* out = (float*)d_out;
  char* ws = (char*)d_ws;
  signed char* wq = (signed char*)ws;
  float* scales = (float*)(ws + SCALES_OFF);
  signed char* xbt = (signed char*)(ws + XBT_OFF);
  float* absm = (float*)(ws + ABSM_OFF);
  float* inK = (float*)(ws + INK_OFF);

  k_prep_w<<<COUT, 256, 0, stream>>>(w, wq, scales);
  k_binz<<<dim3(HPAD, 5), 256, 0, stream>>>(x, xbt, absm);
  k_inputk<<<256, 256, 0, stream>>>(absm, inK);
  k_conv8<<<512, 512, 0, stream>>>(wq, xbt, scales, inK, out);
}

// Round 13
// 108.588 us; speedup vs baseline: 2.0501x; 1.0162x over previous
//
#include <hip/hip_runtime.h>

typedef unsigned short UST;
typedef unsigned int u32;
typedef __attribute__((ext_vector_type(4))) int i32x4;

#define HPAD 258
#define CIN 256
#define COUT 512
#define KTOT 2304  // 256*9

// workspace partition (bytes)
#define SCALES_OFF (COUT * KTOT)           // 1,179,648 (i8 weights first)
#define XBT_OFF    (SCALES_OFF + 2048)     // 1,181,696 (16B aligned)
#define XBT_BYTES  (HPAD * HPAD * CIN)     // 17,040,384 (i8)
#define ABSM_OFF   (XBT_OFF + XBT_BYTES)
#define ABSM_BYTES (HPAD * HPAD * 4)
#define INK_OFF    (ABSM_OFF + ABSM_BYTES)

__device__ __forceinline__ void gload_lds16(const void* g, void* l) {
  __builtin_amdgcn_global_load_lds(
      (const __attribute__((address_space(1))) u32*)g,
      (__attribute__((address_space(3))) u32*)l, 16, 0, 0);
}

// ---- kernel 1: per-channel i8 quant + alpha-fold scale ----
__global__ __launch_bounds__(256) void k_prep_w(const float* __restrict__ w,
                                                signed char* __restrict__ wq,
                                                float* __restrict__ scales) {
  int co = blockIdx.x;
  int ci = threadIdx.x;
  const float* wr = w + co * KTOT + ci * 9;
  float v[9];
  float s = 0.f, mx = 0.f;
#pragma unroll
  for (int j = 0; j < 9; ++j) {
    v[j] = wr[j]; s += v[j]; mx = fmaxf(mx, fabsf(v[j]));
  }
  __shared__ float redS[256];
  __shared__ float redM[256];
  redS[ci] = s; redM[ci] = mx;
  __syncthreads();
#pragma unroll
  for (int off = 128; off > 0; off >>= 1) {
    if (ci < off) {
      redS[ci] += redS[ci + off];
      redM[ci] = fmaxf(redM[ci], redM[ci + off]);
    }
    __syncthreads();
  }
  float alpha = redS[0] * (1.0f / 2304.0f);
  float maxw = redM[0];
  float inv = 127.0f / maxw;
  signed char* wo = wq + co * KTOT + ci;
#pragma unroll
  for (int j = 0; j < 9; ++j)
    wo[j * 256] = (signed char)__float2int_rn(v[j] * inv);
  if (ci == 0) scales[co] = alpha * maxw * (1.0f / 127.0f);
}

// ---- kernel 2: binarize to i8 (+1/-1) NHWC + channel-mean |x| ----
__global__ __launch_bounds__(256) void k_binz(const float* __restrict__ x,
                                              signed char* __restrict__ xbt,
                                              float* __restrict__ absm) {
  int hp = blockIdx.x;
  int wt = blockIdx.y;
  int wpl = threadIdx.x & 63;
  int chunk = threadIdx.x >> 6;
  int wp = wt * 64 + wpl;
  bool valid = wp < HPAD;
  int hx = hp - 1, wx = wp - 1;
  bool inb = valid && ((unsigned)hx < 256u) && ((unsigned)wx < 256u);
  float asum = 0.f;
  u32 pk[16];
#pragma unroll
  for (int c4 = 0; c4 < 16; ++c4) {
    u32 word = 0;
#pragma unroll
    for (int b = 0; b < 4; ++b) {
      int ci = chunk * 64 + c4 * 4 + b;
      float v = 1.0f;
      if (inb) v = x[(unsigned)ci * 65536u + (unsigned)(hx * 256 + wx)];
      asum += fabsf(v);
      u32 byte = (v >= 0.f) ? 0x01u : 0xFFu;
      word |= byte << (8 * b);
    }
    pk[c4] = word;
  }
  if (valid) {
    uint4* dst = (uint4*)(xbt + (unsigned)(hp * HPAD + wp) * 256u + chunk * 64);
#pragma unroll
    for (int g = 0; g < 4; ++g)
      dst[g] = make_uint4(pk[g * 4], pk[g * 4 + 1], pk[g * 4 + 2], pk[g * 4 + 3]);
  }
  __shared__ float red[4][64];
  red[chunk][wpl] = asum;
  __syncthreads();
  if (chunk == 0 && valid) {
    float tot = red[0][wpl] + red[1][wpl] + red[2][wpl] + red[3][wpl];
    absm[hp * HPAD + wp] = tot * (1.0f / 256.0f);
  }
}

// ---- kernel 3: 3x3 box filter / 9 ----
__global__ __launch_bounds__(256) void k_inputk(const float* __restrict__ absm,
                                                float* __restrict__ inK) {
  int h = blockIdx.x, w = threadIdx.x;
  float s = 0.f;
#pragma unroll
  for (int dh = 0; dh < 3; ++dh)
#pragma unroll
    for (int dw = 0; dw < 3; ++dw) s += absm[(h + dh) * HPAD + (w + dw)];
  inK[h * 256 + w] = s * (1.0f / 9.0f);
}

// ---- kernel 4: 256x256-tile i8 conv, counted-vmcnt, A 2-buf + B 3-ring ----
// LDS = 160 KiB: A bufs lds + S*32768 (S=0,1); B slots lds+65536+S*32768 (0..2).
// Buf = 256 rows x 128 k i8; row = 128 B = 8 slots of 16 B; XOR swizzle
// byte = row*128 + (slot^(row&7))*16 (verified conflict-free 16-row pattern).
// Per tile u: stage A(u+1) (4 DMA) + B(u+2) (4 DMA); boundary
// lgkmcnt(0)+vmcnt(4) -- only B(u+2) stays in flight across the barrier;
// trailing reads of tile u+1's first frag group + trailing MF_HI fill the
// post-barrier window. 18 K-tiles of 128.
#define MMI(a, b, c) __builtin_amdgcn_mfma_i32_16x16x64_i8(a, b, c, 0, 0, 0)

#define A_LDS(S) (lds + (S) * 32768)
#define B_LDS(S) (lds + 65536 + (S) * 32768)
#define RD_A(S, KS, M) (*(const i32x4*)(A_LDS(S) + swzA[KS][M]))
#define RD_B(S, KS, N) (*(const i32x4*)(B_LDS(S) + swzB[KS][N]))

#define STAGE_A(SRC, S) do { \
    char* d_ = A_LDS(S) + wv * 1024; \
    gload_lds16((SRC) + aoff[0], d_); \
    gload_lds16((SRC) + aoff[1], d_ + 8192); \
    gload_lds16((SRC) + aoff[2], d_ + 16384); \
    gload_lds16((SRC) + aoff[3], d_ + 24576); } while (0)

#define STAGE_B(SRC, S) do { \
    char* d_ = B_LDS(S) + wv * 1024; \
    gload_lds16((SRC) + boff[0], d_); \
    gload_lds16((SRC) + boff[1], d_ + 8192); \
    gload_lds16((SRC) + boff[2], d_ + 16384); \
    gload_lds16((SRC) + boff[3], d_ + 24576); } while (0)

#define SB __builtin_amdgcn_sched_barrier(0)
#define VMW(N) asm volatile("s_waitcnt vmcnt(" #N ")" ::: "memory")
#define LGK0 asm volatile("s_waitcnt lgkmcnt(0)" ::: "memory")

#define RDB4(S, KS, D) \
  D[0] = RD_B(S, KS, 0); D[1] = RD_B(S, KS, 1); \
  D[2] = RD_B(S, KS, 2); D[3] = RD_B(S, KS, 3);
#define RDALO(S, KS, D) \
  D[0] = RD_A(S, KS, 0); D[1] = RD_A(S, KS, 1); \
  D[2] = RD_A(S, KS, 2); D[3] = RD_A(S, KS, 3);
#define RDAHI(S, KS, D) \
  D[0] = RD_A(S, KS, 4); D[1] = RD_A(S, KS, 5); \
  D[2] = RD_A(S, KS, 6); D[3] = RD_A(S, KS, 7);

#define MF_LO(AA, BB) \
  __builtin_amdgcn_s_setprio(1); \
  _Pragma("unroll") for (int m = 0; m < 4; ++m) \
  _Pragma("unroll") for (int n = 0; n < 4; ++n) \
    acc[m][n] = MMI(AA[m], BB[n], acc[m][n]); \
  __builtin_amdgcn_s_setprio(0);
#define MF_HI(AA, BB) \
  __builtin_amdgcn_s_setprio(1); \
  _Pragma("unroll") for (int m = 0; m < 4; ++m) \
  _Pragma("unroll") for (int n = 0; n < 4; ++n) \
    acc[m + 4][n] = MMI(AA[m], BB[n], acc[m + 4][n]); \
  __builtin_amdgcn_s_setprio(0);

// B source base for K-tile TT (literal): khkw group = TT>>1, ci-half = TT&1
#define BGPX(TT) (xbt_b + ((h + ((TT) >> 1) / 3) * HPAD + (((TT) >> 1) % 3)) * 256 \
                  + ((TT) & 1) * 128)

// carried: B0_[4], Alo_[4] = tile-u ks0 B frags and A(m0-3) frags
#define BODY(CA, CB, SA, SBT, TA, TB, ASRC, BSRC) do { \
  i32x4 Ahi_[4], B1_[4], A1lo_[4], A1hi_[4]; \
  RDAHI(CA, 0, Ahi_); \
  STAGE_A((ASRC), SA); STAGE_B((BSRC), SBT); \
  SB; MF_LO(Alo_, B0_); SB; \
  RDB4(CB, 1, B1_); RDALO(CA, 1, A1lo_); \
  SB; MF_HI(Ahi_, B0_); SB; \
  RDAHI(CA, 1, A1hi_); \
  SB; MF_LO(A1lo_, B1_); SB; \
  LGK0; VMW(4); \
  __builtin_amdgcn_s_barrier(); \
  RDB4(TB, 0, B0_); RDALO(TA, 0, Alo_); \
  SB; MF_HI(A1hi_, B1_); SB; \
} while (0)

#define BU(U) BODY((U) & 1, (U) % 3, ((U) + 1) & 1, ((U) + 2) % 3, \
                   ((U) + 1) & 1, ((U) + 1) % 3, \
                   wb_b + ((U) + 1) * 128, BGPX((U) + 2))

// u = 16: stage A(17) only (B(17) staged at u=15); drain fully
#define BODY16() do { \
  i32x4 Ahi_[4], B1_[4], A1lo_[4], A1hi_[4]; \
  RDAHI(0, 0, Ahi_); \
  STAGE_A(wb_b + 17 * 128, 1); \
  SB; MF_LO(Alo_, B0_); SB; \
  RDB4(1, 1, B1_); RDALO(0, 1, A1lo_); \
  SB; MF_HI(Ahi_, B0_); SB; \
  RDAHI(0, 1, A1hi_); \
  SB; MF_LO(A1lo_, B1_); SB; \
  LGK0; VMW(0); \
  __builtin_amdgcn_s_barrier(); \
  RDB4(2, 0, B0_); RDALO(1, 0, Alo_); \
  SB; MF_HI(A1hi_, B1_); SB; \
} while (0)

// u = 17: final tile
#define BODY17() do { \
  i32x4 Ahi_[4], B1_[4], A1lo_[4], A1hi_[4]; \
  RDAHI(1, 0, Ahi_); \
  SB; MF_LO(Alo_, B0_); SB; \
  RDB4(2, 1, B1_); RDALO(1, 1, A1lo_); \
  SB; MF_HI(Ahi_, B0_); SB; \
  RDAHI(1, 1, A1hi_); \
  SB; MF_LO(A1lo_, B1_); SB; \
  SB; MF_HI(A1hi_, B1_); SB; \
} while (0)

__global__ __launch_bounds__(512, 1) void k_conv8(const signed char* __restrict__ wq,
                                                  const signed char* __restrict__ xbt,
                                                  const float* __restrict__ scales,
                                                  const float* __restrict__ inK,
                                                  float* __restrict__ out) {
  __shared__ __align__(16) char lds[163840];
  int tid = threadIdx.x;
  int lane = tid & 63;
  int wv = tid >> 6;
  int wm = wv >> 2, wn = wv & 3;
  int bid = blockIdx.x;
  int bs = (bid & 7) * 64 + (bid >> 3);  // XCD-bijective swizzle (512 % 8 == 0)
  int mt = bs & 1;
  int h = bs >> 1;
  int co0 = mt << 8;

  // staging offsets: inverse-swizzled global source, linear LDS dest
  int aoff[4], boff[4];
#pragma unroll
  for (int i = 0; i < 4; ++i) {
    u32 ql = (u32)(i * 512 + tid) * 16u;
    u32 row = ql >> 7;
    u32 s = (ql >> 4) & 7u;
    u32 slot = s ^ (row & 7u);
    aoff[i] = (int)((co0 + row) * 2304u + slot * 16u);
    boff[i] = (int)(row * 256u + slot * 16u);
  }
  // ds_read swizzled offsets: [ks][frag]
  int swzA[2][8], swzB[2][4];
#pragma unroll
  for (int ks = 0; ks < 2; ++ks) {
#pragma unroll
    for (int m = 0; m < 8; ++m) {
      u32 row = (u32)(wm * 128 + m * 16 + (lane & 15));
      u32 slot = (u32)(ks * 4 + (lane >> 4));
      swzA[ks][m] = (int)(row * 128u + (slot ^ (row & 7u)) * 16u);
    }
#pragma unroll
    for (int n = 0; n < 4; ++n) {
      u32 row = (u32)(wn * 64 + n * 16 + (lane & 15));
      u32 slot = (u32)(ks * 4 + (lane >> 4));
      swzB[ks][n] = (int)(row * 128u + (slot ^ (row & 7u)) * 16u);
    }
  }

  const char* wb_b = (const char*)wq;
  const char* xbt_b = (const char*)xbt;

  i32x4 acc[8][4];
#pragma unroll
  for (int m = 0; m < 8; ++m)
#pragma unroll
    for (int n = 0; n < 4; ++n) acc[m][n] = (i32x4){0, 0, 0, 0};

  i32x4 B0_[4], Alo_[4];

  // prologue: A(0)->buf0, B(0)->slot0, B(1)->slot1; wait A0+B0 (B1 in flight)
  STAGE_A(wb_b, 0);
  STAGE_B(BGPX(0), 0);
  STAGE_B(BGPX(1), 1);
  VMW(4);
  __builtin_amdgcn_s_barrier();
  RDB4(0, 0, B0_); RDALO(0, 0, Alo_);

  BU(0); BU(1); BU(2); BU(3); BU(4); BU(5); BU(6); BU(7);
  BU(8); BU(9); BU(10); BU(11); BU(12); BU(13); BU(14); BU(15);
  BODY16();
  BODY17();

  // epilogue: out = acc * scale[co] * input_K, write NCHW
  int col = lane & 15, rg = lane >> 4;
  int pixbase = h * 256;
#pragma unroll
  for (int n = 0; n < 4; ++n) {
    int w = wn * 64 + n * 16 + col;
    float kv = inK[pixbase + w];
#pragma unroll
    for (int m = 0; m < 8; ++m) {
      int cobase = co0 + wm * 128 + m * 16 + rg * 4;
      float4 scv = *(const float4*)(scales + cobase);
      float* o = out + (u32)cobase * 65536u + (u32)(pixbase + w);
      o[0]           = (float)acc[m][n][0] * scv.x * kv;
      o[65536u]      = (float)acc[m][n][1] * scv.y * kv;
      o[2u * 65536u] = (float)acc[m][n][2] * scv.z * kv;
      o[3u * 65536u] = (float)acc[m][n][3] * scv.w * kv;
    }
  }
}

extern "C" void kernel_launch(void* const* d_in, const int* in_sizes, int n_in,
                              void* d_out, int out_size, void* d_ws, size_t ws_size,
                              hipStream_t stream) {
  const float* x = (const float*)d_in[0];
  const float* w = (const float*)d_in[1];
  float* out = (float*)d_out;
  char* ws = (char*)d_ws;
  signed char* wq = (signed char*)ws;
  float* scales = (float*)(ws + SCALES_OFF);
  signed char* xbt = (signed char*)(ws + XBT_OFF);
  float* absm = (float*)(ws + ABSM_OFF);
  float* inK = (float*)(ws + INK_OFF);

  k_prep_w<<<COUT, 256, 0, stream>>>(w, wq, scales);
  k_binz<<<dim3(HPAD, 5), 256, 0, stream>>>(x, xbt, absm);
  k_inputk<<<256, 256, 0, stream>>>(absm, inK);
  k_conv8<<<512, 512, 0, stream>>>(wq, xbt, scales, inK, out);
}